// Round 2
// baseline (311.529 us; speedup 1.0000x reference)
//
#include <hip/hip_runtime.h>

#define NROWS  65536
#define CDIM   128
#define MKEYS  1024
#define BROWS  64          // rows per block
#define NBLK   (NROWS / BROWS)

typedef _Float16 half8  __attribute__((ext_vector_type(8)));
typedef float    floatx4 __attribute__((ext_vector_type(4)));

union FU { float f; unsigned u; };

// ---------------------------------------------------------------------------
// Prep: build frag-major fp16 split keys in ws.
// frag index f = (s*4 + kk)*2 + t   (s = 16-key subtile 0..63, kk = K-chunk 0..3,
// t: 0 = kh = fp16(k), 1 = kl = fp16(k - kh)).  Each frag = 1 KB: lane l holds
// A[m = l&15][k = kk*32 + (l>>4)*8 + j]  at  f*1024 + l*16 bytes.
// A-fragment loads in the main kernel are then perfectly coalesced (lane*16).
// ---------------------------------------------------------------------------
__global__ __launch_bounds__(256) void prep_keys(const float* __restrict__ keys,
                                                 _Float16* __restrict__ kf) {
    int t    = threadIdx.x;
    int p    = blockIdx.x * 4 + (t >> 6);   // p = s*4 + kk, 0..255
    int lane = t & 63;
    int s    = p >> 2, kk = p & 3;
    int n    = lane & 15, quad = lane >> 4;
    const float* src = keys + (size_t)(s * 16 + n) * CDIM + kk * 32 + quad * 8;
    float4 a = *(const float4*)(src);
    float4 b = *(const float4*)(src + 4);
    float v[8] = {a.x, a.y, a.z, a.w, b.x, b.y, b.z, b.w};
    half8 h, l;
#pragma unroll
    for (int j = 0; j < 8; ++j) {
        _Float16 hv = (_Float16)v[j];
        h[j] = hv;
        l[j] = (_Float16)(v[j] - (float)hv);
    }
    ((half8*)(kf + (size_t)(p * 2) * 512))[lane]     = h;   // kh frag
    ((half8*)(kf + (size_t)(p * 2 + 1) * 512))[lane] = l;   // kl frag
}

// ---------------------------------------------------------------------------
// Main: 64 rows/block, 256 threads (4 waves). Wave w sweeps keys
// [w*256, w*256+256) for ALL 64 rows (4 row-tiles). Scores via 2-term fp16
// MFMA (qh·kh + qh·kl); per-lane top-2 w/ indices; tiered exact rescue.
// ---------------------------------------------------------------------------
__global__ __launch_bounds__(256, 3) void gather_main(
    const float* __restrict__ q,
    const float* __restrict__ rep,
    const float* __restrict__ keys,
    const float* __restrict__ vals,
    const _Float16* __restrict__ kf,
    float* __restrict__ out)
{
    // LDS: qh staging reused as top-2 tuple area after the hoist barrier.
    union ShMem {
        _Float16 qh[BROWS * CDIM];      // 16 KB  (fp16 q tile, phase 1)
        float4   tup[BROWS * 16];       // 16 KB  (per-lane top-2 tuples, phase 3)
    };
    __shared__ ShMem U;
    __shared__ float qssp[256];
    __shared__ int   rowIdx[BROWS];
    __shared__ int   candList[BROWS][8];
    __shared__ int   clCnt[BROWS];
    __shared__ int   fsList[BROWS];
    __shared__ int   fsCnt;
    __shared__ unsigned long long rowBest[BROWS];
    __shared__ float kgp[256], vgp[256];

    const int t    = threadIdx.x;
    const int w    = t >> 6;          // wave 0..3 -> key quarter
    const int lane = t & 63;
    const int n    = lane & 15;       // q-row within row-tile / frag row
    const int q4   = lane >> 4;       // key sub-group in C layout
    const long g0  = (long)blockIdx.x * BROWS;

    if (t == 0) fsCnt = 0;

    // ---- P1: stage q tile -> fp16 LDS (row-major), per-thread sumsq ----
    {
        int r = t >> 2, qt = t & 3;           // 64 rows x 4 quarters of 32
        const float* src = q + (g0 + r) * CDIM + qt * 32;
        float ss = 0.f;
#pragma unroll
        for (int i = 0; i < 4; ++i) {
            float4 a = ((const float4*)src)[i * 2];
            float4 b = ((const float4*)src)[i * 2 + 1];
            ss += a.x*a.x + a.y*a.y + a.z*a.z + a.w*a.w
                + b.x*b.x + b.y*b.y + b.z*b.z + b.w*b.w;
            half8 hv;
            hv[0]=(_Float16)a.x; hv[1]=(_Float16)a.y; hv[2]=(_Float16)a.z; hv[3]=(_Float16)a.w;
            hv[4]=(_Float16)b.x; hv[5]=(_Float16)b.y; hv[6]=(_Float16)b.z; hv[7]=(_Float16)b.w;
            *(half8*)&U.qh[r * CDIM + qt * 32 + i * 8] = hv;
        }
        qssp[t] = ss;
    }
    __syncthreads();

    // ---- P2: hoist q B-fragments to registers (all 4 row-tiles x 4 kk) ----
    half8 qf[4][4];
#pragma unroll
    for (int rt = 0; rt < 4; ++rt)
#pragma unroll
        for (int kk = 0; kk < 4; ++kk)
            qf[rt][kk] = *(const half8*)&U.qh[(rt * 16 + n) * CDIM + kk * 32 + q4 * 8];
    __syncthreads();   // qh area is dead; tup area may now be written

    // ---- P3: barrier-free key sweep. 16 subtiles x (8 loads -> 32 MFMA) ----
    float m1[4], m2[4]; int i1[4], i2[4];
#pragma unroll
    for (int rt = 0; rt < 4; ++rt) { m1[rt] = -3.4e38f; m2[rt] = -3.4e38f; i1[rt] = 0; i2[rt] = 0; }

    for (int st = 0; st < 16; ++st) {
        int s = w * 16 + st;                       // global 16-key subtile
        const half8* fb = (const half8*)(kf + (size_t)s * 4096);
        half8 f0 = fb[0 * 64 + lane], f1 = fb[1 * 64 + lane];
        half8 f2 = fb[2 * 64 + lane], f3 = fb[3 * 64 + lane];
        half8 f4 = fb[4 * 64 + lane], f5 = fb[5 * 64 + lane];
        half8 f6 = fb[6 * 64 + lane], f7 = fb[7 * 64 + lane];

        floatx4 a0 = {0,0,0,0}, a1 = {0,0,0,0}, a2 = {0,0,0,0}, a3 = {0,0,0,0};
        // kk0
        a0 = __builtin_amdgcn_mfma_f32_16x16x32_f16(f0, qf[0][0], a0, 0,0,0);
        a1 = __builtin_amdgcn_mfma_f32_16x16x32_f16(f0, qf[1][0], a1, 0,0,0);
        a2 = __builtin_amdgcn_mfma_f32_16x16x32_f16(f0, qf[2][0], a2, 0,0,0);
        a3 = __builtin_amdgcn_mfma_f32_16x16x32_f16(f0, qf[3][0], a3, 0,0,0);
        a0 = __builtin_amdgcn_mfma_f32_16x16x32_f16(f1, qf[0][0], a0, 0,0,0);
        a1 = __builtin_amdgcn_mfma_f32_16x16x32_f16(f1, qf[1][0], a1, 0,0,0);
        a2 = __builtin_amdgcn_mfma_f32_16x16x32_f16(f1, qf[2][0], a2, 0,0,0);
        a3 = __builtin_amdgcn_mfma_f32_16x16x32_f16(f1, qf[3][0], a3, 0,0,0);
        // kk1
        a0 = __builtin_amdgcn_mfma_f32_16x16x32_f16(f2, qf[0][1], a0, 0,0,0);
        a1 = __builtin_amdgcn_mfma_f32_16x16x32_f16(f2, qf[1][1], a1, 0,0,0);
        a2 = __builtin_amdgcn_mfma_f32_16x16x32_f16(f2, qf[2][1], a2, 0,0,0);
        a3 = __builtin_amdgcn_mfma_f32_16x16x32_f16(f2, qf[3][1], a3, 0,0,0);
        a0 = __builtin_amdgcn_mfma_f32_16x16x32_f16(f3, qf[0][1], a0, 0,0,0);
        a1 = __builtin_amdgcn_mfma_f32_16x16x32_f16(f3, qf[1][1], a1, 0,0,0);
        a2 = __builtin_amdgcn_mfma_f32_16x16x32_f16(f3, qf[2][1], a2, 0,0,0);
        a3 = __builtin_amdgcn_mfma_f32_16x16x32_f16(f3, qf[3][1], a3, 0,0,0);
        // kk2
        a0 = __builtin_amdgcn_mfma_f32_16x16x32_f16(f4, qf[0][2], a0, 0,0,0);
        a1 = __builtin_amdgcn_mfma_f32_16x16x32_f16(f4, qf[1][2], a1, 0,0,0);
        a2 = __builtin_amdgcn_mfma_f32_16x16x32_f16(f4, qf[2][2], a2, 0,0,0);
        a3 = __builtin_amdgcn_mfma_f32_16x16x32_f16(f4, qf[3][2], a3, 0,0,0);
        a0 = __builtin_amdgcn_mfma_f32_16x16x32_f16(f5, qf[0][2], a0, 0,0,0);
        a1 = __builtin_amdgcn_mfma_f32_16x16x32_f16(f5, qf[1][2], a1, 0,0,0);
        a2 = __builtin_amdgcn_mfma_f32_16x16x32_f16(f5, qf[2][2], a2, 0,0,0);
        a3 = __builtin_amdgcn_mfma_f32_16x16x32_f16(f5, qf[3][2], a3, 0,0,0);
        // kk3
        a0 = __builtin_amdgcn_mfma_f32_16x16x32_f16(f6, qf[0][3], a0, 0,0,0);
        a1 = __builtin_amdgcn_mfma_f32_16x16x32_f16(f6, qf[1][3], a1, 0,0,0);
        a2 = __builtin_amdgcn_mfma_f32_16x16x32_f16(f6, qf[2][3], a2, 0,0,0);
        a3 = __builtin_amdgcn_mfma_f32_16x16x32_f16(f6, qf[3][3], a3, 0,0,0);
        a0 = __builtin_amdgcn_mfma_f32_16x16x32_f16(f7, qf[0][3], a0, 0,0,0);
        a1 = __builtin_amdgcn_mfma_f32_16x16x32_f16(f7, qf[1][3], a1, 0,0,0);
        a2 = __builtin_amdgcn_mfma_f32_16x16x32_f16(f7, qf[2][3], a2, 0,0,0);
        a3 = __builtin_amdgcn_mfma_f32_16x16x32_f16(f7, qf[3][3], a3, 0,0,0);

        int kbase = s * 16 + q4 * 4;
        floatx4 aa[4] = {a0, a1, a2, a3};
#pragma unroll
        for (int rt = 0; rt < 4; ++rt) {
#pragma unroll
            for (int reg = 0; reg < 4; ++reg) {
                float sv = aa[rt][reg]; int kid = kbase + reg;
                bool c1 = sv > m1[rt];
                bool c2 = sv > m2[rt];
                m2[rt] = c1 ? m1[rt] : (c2 ? sv  : m2[rt]);
                i2[rt] = c1 ? i1[rt] : (c2 ? kid : i2[rt]);
                m1[rt] = c1 ? sv  : m1[rt];
                i1[rt] = c1 ? kid : i1[rt];
            }
        }
    }

    // ---- P4: publish per-lane top-2 tuples (row = rt*16+n, entry = w*4+q4) ----
#pragma unroll
    for (int rt = 0; rt < 4; ++rt) {
        U.tup[(rt * 16 + n) * 16 + (w * 4 + q4)] =
            make_float4(m1[rt], __int_as_float(i1[rt]), m2[rt], __int_as_float(i2[rt]));
    }
    __syncthreads();

    // ---- P5: per-row owner merges 16 entries; tier decision ----
    if (t < BROWS) {
        float M1 = -3.4e38f; int I1 = 0;
        for (int e = 0; e < 16; ++e) {
            float4 v = U.tup[t * 16 + e];
            int vi = __float_as_int(v.y);
            if (v.x > M1 || (v.x == M1 && vi < I1)) { M1 = v.x; I1 = vi; }
        }
        float qn2 = qssp[t*4] + qssp[t*4+1] + qssp[t*4+2] + qssp[t*4+3];
        // |s~ - s| <= 2^-11 * ||q|| * Kmax(<=16) + acc/subnormal slack
        float thr = M1 - (0.0157f * sqrtf(qn2) + 0.04f);
        bool fs = false; int cnt = 1;
        candList[t][0] = I1;
        for (int e = 0; e < 16; ++e) {
            float4 v = U.tup[t * 16 + e];
            if (v.z >= thr) fs = true;                 // hidden 3rd possible in that lane
            int vi = __float_as_int(v.y);
            if (v.x >= thr && vi != I1) {
                if (cnt < 8) candList[t][cnt] = vi;
                cnt++;
            }
        }
        if (cnt > 8) fs = true;
        rowIdx[t]  = I1;
        rowBest[t] = 0ull;
        clCnt[t]   = fs ? -1 : cnt;
        if (fs) { int p = atomicAdd(&fsCnt, 1); fsList[p] = t; }
    }
    __syncthreads();

    // ---- P6: tier-1 — exact fp32 rescore of small candidate sets ----
    if (t < BROWS && clCnt[t] >= 2) {
        const float* qp = q + (g0 + t) * CDIM;
        float best = -3.4e38f; int bi = 0;
        int cnt = clCnt[t];
        for (int c = 0; c < cnt; ++c) {
            int key = candList[t][c];
            const float* kp = keys + (size_t)key * CDIM;
            float acc0 = 0.f, acc1 = 0.f;
            for (int cc = 0; cc < CDIM; cc += 8) {
                float4 qa = *(const float4*)(qp + cc);
                float4 ka = *(const float4*)(kp + cc);
                float4 qb = *(const float4*)(qp + cc + 4);
                float4 kb = *(const float4*)(kp + cc + 4);
                acc0 += qa.x*ka.x + qa.y*ka.y + qa.z*ka.z + qa.w*ka.w;
                acc1 += qb.x*kb.x + qb.y*kb.y + qb.z*kb.z + qb.w*kb.w;
            }
            float sd = acc0 + acc1;
            if (sd > best || (sd == best && key < bi)) { best = sd; bi = key; }
        }
        rowIdx[t] = bi;
    }

    // ---- P7: tier-2 — rare full exact rescan (block-cooperative) ----
    for (int fi = 0; fi < fsCnt; ++fi) {
        int r = fsList[fi];
        const float* qp = q + (g0 + r) * CDIM;
#pragma unroll
        for (int k4 = 0; k4 < 4; ++k4) {
            int key = t * 4 + k4;
            const float* kp = keys + (size_t)key * CDIM;
            float acc0 = 0.f, acc1 = 0.f;
            for (int cc = 0; cc < CDIM; cc += 8) {
                float4 qa = *(const float4*)(qp + cc);
                float4 ka = *(const float4*)(kp + cc);
                float4 qb = *(const float4*)(qp + cc + 4);
                float4 kb = *(const float4*)(kp + cc + 4);
                acc0 += qa.x*ka.x + qa.y*ka.y + qa.z*ka.z + qa.w*ka.w;
                acc1 += qb.x*kb.x + qb.y*kb.y + qb.z*kb.z + qb.w*kb.w;
            }
            FU su; su.f = acc0 + acc1;
            unsigned ord = (su.u & 0x80000000u) ? ~su.u : (su.u | 0x80000000u);
            unsigned long long enc = ((unsigned long long)ord << 32) | (unsigned)(1023 - key);
            atomicMax(&rowBest[r], enc);
        }
    }
    __syncthreads();
    if (t < BROWS && clCnt[t] == -1) {
        rowIdx[t] = 1023 - (int)(unsigned)(rowBest[t] & 0xffffffffull);
    }
    __syncthreads();

    // ---- P8: fused gather: sum (q-k)^2 and (r-v)^2 in fp32 ----
    {
        int r = t >> 2, qt = t & 3;
        int idx = rowIdx[r];
        long g = g0 + r;
        const float4* qp = (const float4*)(q    + g * CDIM + qt * 32);
        const float4* kp = (const float4*)(keys + (size_t)idx * CDIM + qt * 32);
        const float4* rp = (const float4*)(rep  + g * CDIM + qt * 32);
        const float4* vp = (const float4*)(vals + (size_t)idx * CDIM + qt * 32);
        float kg = 0.f, vg = 0.f;
#pragma unroll
        for (int h = 0; h < 8; ++h) {
            float4 qa = qp[h], ka = kp[h];
            float d0 = qa.x-ka.x, d1 = qa.y-ka.y, d2 = qa.z-ka.z, d3 = qa.w-ka.w;
            kg += d0*d0 + d1*d1 + d2*d2 + d3*d3;
            float4 ra = rp[h], va = vp[h];
            float e0 = ra.x-va.x, e1 = ra.y-va.y, e2 = ra.z-va.z, e3 = ra.w-va.w;
            vg += e0*e0 + e1*e1 + e2*e2 + e3*e3;
        }
        kgp[t] = kg; vgp[t] = vg;
    }
    __syncthreads();
    if (t < BROWS) {
        float a = kgp[t*4] + kgp[t*4+1] + kgp[t*4+2] + kgp[t*4+3];
        float b = vgp[t*4] + vgp[t*4+1] + vgp[t*4+2] + vgp[t*4+3];
        out[g0 + t]         = a;
        out[NROWS + g0 + t] = b;
    }
}

extern "C" void kernel_launch(void* const* d_in, const int* in_sizes, int n_in,
                              void* d_out, int out_size, void* d_ws, size_t ws_size,
                              hipStream_t stream) {
    const float* q    = (const float*)d_in[0];  // trend_representation
    const float* rep  = (const float*)d_in[1];  // representation
    const float* keys = (const float*)d_in[2];
    const float* vals = (const float*)d_in[3];
    _Float16* kf = (_Float16*)d_ws;             // 512 KB frag-major fp16 split keys

    prep_keys<<<64, 256, 0, stream>>>(keys, kf);
    gather_main<<<NBLK, 256, 0, stream>>>(q, rep, keys, vals, kf, (float*)d_out);
}

// Round 3
// 307.520 us; speedup vs baseline: 1.0130x; 1.0130x over previous
//
#include <hip/hip_runtime.h>

#define NROWS  65536
#define CDIM   128
#define MKEYS  1024
#define BROWS  64          // rows per block
#define NBLK   (NROWS / BROWS)

typedef _Float16 half8  __attribute__((ext_vector_type(8)));
typedef float    floatx4 __attribute__((ext_vector_type(4)));

union FU { float f; unsigned u; };

// ---------------------------------------------------------------------------
// Prep: frag-major fp16 keys in ws. frag id p = s*4 + kk (s = 16-key subtile
// 0..63, kk = K-chunk 0..3). Each frag = 1 KB: lane l holds
// A[m = l&15][k = kk*32 + (l>>4)*8 + j] at p*1024 + l*16 bytes -> the main
// kernel's A-fragment loads are perfectly coalesced (lane*16).
// ---------------------------------------------------------------------------
__global__ __launch_bounds__(256) void prep_keys(const float* __restrict__ keys,
                                                 _Float16* __restrict__ kf) {
    int t    = threadIdx.x;
    int p    = blockIdx.x * 4 + (t >> 6);   // 0..255
    int lane = t & 63;
    int s    = p >> 2, kk = p & 3;
    int n    = lane & 15, quad = lane >> 4;
    const float* src = keys + (size_t)(s * 16 + n) * CDIM + kk * 32 + quad * 8;
    float4 a = *(const float4*)(src);
    float4 b = *(const float4*)(src + 4);
    half8 h;
    h[0]=(_Float16)a.x; h[1]=(_Float16)a.y; h[2]=(_Float16)a.z; h[3]=(_Float16)a.w;
    h[4]=(_Float16)b.x; h[5]=(_Float16)b.y; h[6]=(_Float16)b.z; h[7]=(_Float16)b.w;
    ((half8*)(kf + (size_t)p * 512))[lane] = h;
}

// packed top-2 update: p = (bits & ~1023) | enc  (enc = 1023 - key id)
#define T2UPD(mm1, mm2, bits, encv)                                          \
    {                                                                        \
        float pf = __uint_as_float(((bits) & 0xFFFFFC00u) | (unsigned)(encv)); \
        float mn = fminf(mm1, pf);                                           \
        mm2 = fmaxf(mm2, mn);                                                \
        mm1 = fmaxf(mm1, pf);                                                \
    }

// ---------------------------------------------------------------------------
// Main: 64 rows/block, 4 waves. Wave w sweeps keys [w*256, w*256+256) for all
// 4 row-tiles. Single-term fp16 MFMA scores; packed per-lane top-2; tiered
// exact fp32 rescue (proven in R1/R2).
// ---------------------------------------------------------------------------
__global__ __launch_bounds__(256) void gather_main(
    const float* __restrict__ q,
    const float* __restrict__ rep,
    const float* __restrict__ keys,
    const float* __restrict__ vals,
    const _Float16* __restrict__ kf,
    float* __restrict__ out)
{
    union ShMem {
        _Float16 qh[BROWS * CDIM];      // 16 KB (fp16 q tile, phase 1/2)
        float2   tup[BROWS * 16];       // 8 KB  (per-lane packed top-2, phase 4+)
    };
    __shared__ ShMem U;
    __shared__ float qssp[256];
    __shared__ int   rowIdx[BROWS];
    __shared__ int   candList[BROWS][8];
    __shared__ int   clCnt[BROWS];
    __shared__ int   fsList[BROWS];
    __shared__ int   fsCnt;
    __shared__ unsigned long long rowBest[BROWS];
    __shared__ float kgp[256], vgp[256];

    const int t    = threadIdx.x;
    const int w    = t >> 6;
    const int lane = t & 63;
    const int n    = lane & 15;       // q-row within row-tile (C col)
    const int q4   = lane >> 4;       // key sub-group (C row group)
    const long g0  = (long)blockIdx.x * BROWS;

    if (t == 0) fsCnt = 0;

    // ---- P1: stage q tile -> fp16 LDS (chunk-swizzled), per-thread sumsq ----
    {
        int r = t >> 2, qt = t & 3;           // 64 rows x 4 quarters of 32
        const float* src = q + (g0 + r) * CDIM + qt * 32;
        float ss = 0.f;
#pragma unroll
        for (int i = 0; i < 4; ++i) {
            float4 a = ((const float4*)src)[i * 2];
            float4 b = ((const float4*)src)[i * 2 + 1];
            ss += a.x*a.x + a.y*a.y + a.z*a.z + a.w*a.w
                + b.x*b.x + b.y*b.y + b.z*b.z + b.w*b.w;
            half8 hv;
            hv[0]=(_Float16)a.x; hv[1]=(_Float16)a.y; hv[2]=(_Float16)a.z; hv[3]=(_Float16)a.w;
            hv[4]=(_Float16)b.x; hv[5]=(_Float16)b.y; hv[6]=(_Float16)b.z; hv[7]=(_Float16)b.w;
            int phys = (qt * 4 + i) ^ (r & 7);
            *(half8*)&U.qh[r * CDIM + phys * 8] = hv;
        }
        qssp[t] = ss;
    }
    __syncthreads();

    // ---- P2: hoist q B-fragments to registers (4 row-tiles x 4 kk) ----
    half8 qf[4][4];
#pragma unroll
    for (int rt = 0; rt < 4; ++rt)
#pragma unroll
        for (int kk = 0; kk < 4; ++kk) {
            int phys = (kk * 4 + q4) ^ (n & 7);
            qf[rt][kk] = *(const half8*)&U.qh[(rt * 16 + n) * CDIM + phys * 8];
        }
    __syncthreads();   // qh dead; tup area may be written

    // ---- P3: barrier-free key sweep: 16 subtiles x (4 loads -> 16 MFMA) ----
    float m1_0 = -3.4e38f, m1_1 = -3.4e38f, m1_2 = -3.4e38f, m1_3 = -3.4e38f;
    float m2_0 = -3.4e38f, m2_1 = -3.4e38f, m2_2 = -3.4e38f, m2_3 = -3.4e38f;

    for (int st = 0; st < 16; ++st) {
        int s = w * 16 + st;
        const half8* fb = (const half8*)kf + (size_t)s * 256;
        half8 f0 = fb[0 * 64 + lane];
        half8 f1 = fb[1 * 64 + lane];
        half8 f2 = fb[2 * 64 + lane];
        half8 f3 = fb[3 * 64 + lane];

        floatx4 a0 = {0,0,0,0}, a1 = {0,0,0,0}, a2 = {0,0,0,0}, a3 = {0,0,0,0};
        a0 = __builtin_amdgcn_mfma_f32_16x16x32_f16(f0, qf[0][0], a0, 0,0,0);
        a1 = __builtin_amdgcn_mfma_f32_16x16x32_f16(f0, qf[1][0], a1, 0,0,0);
        a2 = __builtin_amdgcn_mfma_f32_16x16x32_f16(f0, qf[2][0], a2, 0,0,0);
        a3 = __builtin_amdgcn_mfma_f32_16x16x32_f16(f0, qf[3][0], a3, 0,0,0);
        a0 = __builtin_amdgcn_mfma_f32_16x16x32_f16(f1, qf[0][1], a0, 0,0,0);
        a1 = __builtin_amdgcn_mfma_f32_16x16x32_f16(f1, qf[1][1], a1, 0,0,0);
        a2 = __builtin_amdgcn_mfma_f32_16x16x32_f16(f1, qf[2][1], a2, 0,0,0);
        a3 = __builtin_amdgcn_mfma_f32_16x16x32_f16(f1, qf[3][1], a3, 0,0,0);
        a0 = __builtin_amdgcn_mfma_f32_16x16x32_f16(f2, qf[0][2], a0, 0,0,0);
        a1 = __builtin_amdgcn_mfma_f32_16x16x32_f16(f2, qf[1][2], a1, 0,0,0);
        a2 = __builtin_amdgcn_mfma_f32_16x16x32_f16(f2, qf[2][2], a2, 0,0,0);
        a3 = __builtin_amdgcn_mfma_f32_16x16x32_f16(f2, qf[3][2], a3, 0,0,0);
        a0 = __builtin_amdgcn_mfma_f32_16x16x32_f16(f3, qf[0][3], a0, 0,0,0);
        a1 = __builtin_amdgcn_mfma_f32_16x16x32_f16(f3, qf[1][3], a1, 0,0,0);
        a2 = __builtin_amdgcn_mfma_f32_16x16x32_f16(f3, qf[2][3], a2, 0,0,0);
        a3 = __builtin_amdgcn_mfma_f32_16x16x32_f16(f3, qf[3][3], a3, 0,0,0);

        int eb = 1023 - (s * 16 + q4 * 4);   // enc = eb - reg
        {
            FU b0, b1, b2, b3;
            b0.f = a0[0]; b1.f = a0[1]; b2.f = a0[2]; b3.f = a0[3];
            T2UPD(m1_0, m2_0, b0.u, eb);
            T2UPD(m1_0, m2_0, b1.u, eb - 1);
            T2UPD(m1_0, m2_0, b2.u, eb - 2);
            T2UPD(m1_0, m2_0, b3.u, eb - 3);
            b0.f = a1[0]; b1.f = a1[1]; b2.f = a1[2]; b3.f = a1[3];
            T2UPD(m1_1, m2_1, b0.u, eb);
            T2UPD(m1_1, m2_1, b1.u, eb - 1);
            T2UPD(m1_1, m2_1, b2.u, eb - 2);
            T2UPD(m1_1, m2_1, b3.u, eb - 3);
            b0.f = a2[0]; b1.f = a2[1]; b2.f = a2[2]; b3.f = a2[3];
            T2UPD(m1_2, m2_2, b0.u, eb);
            T2UPD(m1_2, m2_2, b1.u, eb - 1);
            T2UPD(m1_2, m2_2, b2.u, eb - 2);
            T2UPD(m1_2, m2_2, b3.u, eb - 3);
            b0.f = a3[0]; b1.f = a3[1]; b2.f = a3[2]; b3.f = a3[3];
            T2UPD(m1_3, m2_3, b0.u, eb);
            T2UPD(m1_3, m2_3, b1.u, eb - 1);
            T2UPD(m1_3, m2_3, b2.u, eb - 2);
            T2UPD(m1_3, m2_3, b3.u, eb - 3);
        }
    }

    // ---- P4: publish per-lane packed top-2 (swizzled slots, order-agnostic) ----
    {
        int e = w * 4 + q4;
        int slot = e ^ n;
        U.tup[(0 * 16 + n) * 16 + slot] = make_float2(m1_0, m2_0);
        U.tup[(1 * 16 + n) * 16 + slot] = make_float2(m1_1, m2_1);
        U.tup[(2 * 16 + n) * 16 + slot] = make_float2(m1_2, m2_2);
        U.tup[(3 * 16 + n) * 16 + slot] = make_float2(m1_3, m2_3);
    }
    __syncthreads();

    // ---- P5: per-row owner merges 16 entries; tier decision ----
    if (t < BROWS) {
        float M1 = -3.4e38f;
        for (int e = 0; e < 16; ++e) M1 = fmaxf(M1, U.tup[t * 16 + e].x);
        int I1 = 1023 - (__float_as_int(M1) & 1023);
        float qn2 = qssp[t*4] + qssp[t*4+1] + qssp[t*4+2] + qssp[t*4+3];
        // |s~ - s| <= 2^-10 * ||q|| * Kmax(<=17) + acc slack; x2 (max & cand);
        // + packed-mantissa granularity slack
        float e1  = 0.0168f * sqrtf(qn2) + 0.01f;
        float thr = M1 - (2.f * e1 + 0.05f);
        bool fs = false; int cnt = 1;
        candList[t][0] = I1;
        for (int e = 0; e < 16; ++e) {
            float2 v = U.tup[t * 16 + e];
            if (v.y >= thr) fs = true;               // hidden 3rd possible in that lane
            int vi = 1023 - (__float_as_int(v.x) & 1023);
            if (v.x >= thr && vi != I1) {
                if (cnt < 8) candList[t][cnt] = vi;
                cnt++;
            }
        }
        if (cnt > 8) fs = true;
        rowIdx[t]  = I1;
        rowBest[t] = 0ull;
        clCnt[t]   = fs ? -1 : cnt;
        if (fs) { int p = atomicAdd(&fsCnt, 1); fsList[p] = t; }
    }
    __syncthreads();

    // ---- P6: tier-1 — exact fp32 rescore of small candidate sets ----
    if (t < BROWS && clCnt[t] >= 2) {
        const float* qp = q + (g0 + t) * CDIM;
        float best = -3.4e38f; int bi = 0;
        int cnt = clCnt[t];
        for (int c = 0; c < cnt; ++c) {
            int key = candList[t][c];
            const float* kp = keys + (size_t)key * CDIM;
            float acc0 = 0.f, acc1 = 0.f;
            for (int cc = 0; cc < CDIM; cc += 8) {
                float4 qa = *(const float4*)(qp + cc);
                float4 ka = *(const float4*)(kp + cc);
                float4 qb = *(const float4*)(qp + cc + 4);
                float4 kb = *(const float4*)(kp + cc + 4);
                acc0 += qa.x*ka.x + qa.y*ka.y + qa.z*ka.z + qa.w*ka.w;
                acc1 += qb.x*kb.x + qb.y*kb.y + qb.z*kb.z + qb.w*kb.w;
            }
            float sd = acc0 + acc1;
            if (sd > best || (sd == best && key < bi)) { best = sd; bi = key; }
        }
        rowIdx[t] = bi;
    }

    // ---- P7: tier-2 — rare full exact rescan (block-cooperative) ----
    for (int fi = 0; fi < fsCnt; ++fi) {
        int r = fsList[fi];
        const float* qp = q + (g0 + r) * CDIM;
#pragma unroll
        for (int k4 = 0; k4 < 4; ++k4) {
            int key = t * 4 + k4;
            const float* kp = keys + (size_t)key * CDIM;
            float acc0 = 0.f, acc1 = 0.f;
            for (int cc = 0; cc < CDIM; cc += 8) {
                float4 qa = *(const float4*)(qp + cc);
                float4 ka = *(const float4*)(kp + cc);
                float4 qb = *(const float4*)(qp + cc + 4);
                float4 kb = *(const float4*)(kp + cc + 4);
                acc0 += qa.x*ka.x + qa.y*ka.y + qa.z*ka.z + qa.w*ka.w;
                acc1 += qb.x*kb.x + qb.y*kb.y + qb.z*kb.z + qb.w*kb.w;
            }
            FU su; su.f = acc0 + acc1;
            unsigned ord = (su.u & 0x80000000u) ? ~su.u : (su.u | 0x80000000u);
            unsigned long long enc = ((unsigned long long)ord << 32) | (unsigned)(1023 - key);
            atomicMax(&rowBest[r], enc);
        }
    }
    __syncthreads();
    if (t < BROWS && clCnt[t] == -1) {
        rowIdx[t] = 1023 - (int)(unsigned)(rowBest[t] & 0xffffffffull);
    }
    __syncthreads();

    // ---- P8: fused gather: sum (q-k)^2 and (r-v)^2 in fp32 ----
    {
        int r = t >> 2, qt = t & 3;
        int idx = rowIdx[r];
        long g = g0 + r;
        const float4* qp = (const float4*)(q    + g * CDIM + qt * 32);
        const float4* kp = (const float4*)(keys + (size_t)idx * CDIM + qt * 32);
        const float4* rp = (const float4*)(rep  + g * CDIM + qt * 32);
        const float4* vp = (const float4*)(vals + (size_t)idx * CDIM + qt * 32);
        float kg = 0.f, vg = 0.f;
#pragma unroll
        for (int h = 0; h < 8; ++h) {
            float4 qa = qp[h], ka = kp[h];
            float d0 = qa.x-ka.x, d1 = qa.y-ka.y, d2 = qa.z-ka.z, d3 = qa.w-ka.w;
            kg += d0*d0 + d1*d1 + d2*d2 + d3*d3;
            float4 ra = rp[h], va = vp[h];
            float e0 = ra.x-va.x, e1 = ra.y-va.y, e2 = ra.z-va.z, e3 = ra.w-va.w;
            vg += e0*e0 + e1*e1 + e2*e2 + e3*e3;
        }
        kgp[t] = kg; vgp[t] = vg;
    }
    __syncthreads();
    if (t < BROWS) {
        float a = kgp[t*4] + kgp[t*4+1] + kgp[t*4+2] + kgp[t*4+3];
        float b = vgp[t*4] + vgp[t*4+1] + vgp[t*4+2] + vgp[t*4+3];
        out[g0 + t]         = a;
        out[NROWS + g0 + t] = b;
    }
}

extern "C" void kernel_launch(void* const* d_in, const int* in_sizes, int n_in,
                              void* d_out, int out_size, void* d_ws, size_t ws_size,
                              hipStream_t stream) {
    const float* q    = (const float*)d_in[0];  // trend_representation
    const float* rep  = (const float*)d_in[1];  // representation
    const float* keys = (const float*)d_in[2];
    const float* vals = (const float*)d_in[3];
    _Float16* kf = (_Float16*)d_ws;             // 256 KB frag-major fp16 keys

    prep_keys<<<64, 256, 0, stream>>>(keys, kf);
    gather_main<<<NBLK, 256, 0, stream>>>(q, rep, keys, vals, kf, (float*)d_out);
}